// Round 4
// baseline (456.958 us; speedup 1.0000x reference)
//
#include <hip/hip_runtime.h>
#include <cmath>

// Persistent weight-stationary LSTM decode. B=64, H=2048, steps=30.
// gates_t = W_sum @ h_t (t>=1, since x_t == h_t), W_hh @ h_0 at t=0.
// One block per CU (grid=256); weights live in LDS as fp16 MFMA A-frags.
//
// v8 (resubmit; R3 bench was a container-acquisition failure, kernel never
// ran; full deadlock/race/index audit found no defect). Collapsed tail,
// per-step barriers 5 -> 2.
//  - 2-round reduce with 24KB red: {w2,w3,w6,w7} store srows0-3; bar1;
//    {w0,w1} add srows0-1, {w4,w5} add srows2-3 + store srows4-5; bar2;
//    {w0,w1} final-add srows4-5.
//  - gates/hstage/ybuf LDS buffers deleted. Pointwise runs entirely in
//    waves 0,1: one shfl_xor(32) exchange pairs (i,g) rows with (f,o)
//    rows; each lane evaluates 4 units x 1 batch; c in registers.
//  - publish: each lane of waves 0,1 stores its packed 4xf16 as ONE 8B
//    agent-scope atomic (lane pairs q0/q1 fill each 16B piece), then
//    vmcnt(0) + per-(block,half) flag (512 flags). Waves 2-7 skip the
//    tail completely and overlap spin(t+1)+MFMA(t+1) with the publish.
//  - y computed in-register (shfl_xor 16 combine), written off-path.
// Sync scheme otherwise unchanged: agent-scope relaxed atomic h stores,
// vmcnt(0), flag, first-touch cacheable reads of a fresh slot per step
// (each 64B line of a slot belongs to exactly one (producer,half) flag).

#define HID   2048
#define BATCH 64
#define G4    8192
#define NCU   256                 // persistent grid size == CU count
#define HGRP  (HID * BATCH / 8)   // half8 groups per h slot
#define NFLAGS 512                // [half][block]

typedef __attribute__((ext_vector_type(8))) _Float16 half8;
typedef __attribute__((ext_vector_type(4))) float f32x4;

// LDS layout (bytes):
//   [0,      131072)  Wlds : half8 frags [(mt*64+kt)*64+lane]
//   [131072, 155648)  red4 : f32x4 [(srow*4+p)*64+lane]  (6 srows, 24KB)
#define LDS_BYTES 155648

// ---- init: pack token -> h slot 0 (B-fragment layout), bsum, flags ----
__global__ void k_init(const float* __restrict__ token, const float* __restrict__ bih,
                       const float* __restrict__ bhh, half8* __restrict__ h0p,
                       float* __restrict__ bsum, unsigned* __restrict__ flags) {
    int g = blockIdx.x * 256 + threadIdx.x;          // [0, 16384)
    int l = g & 63, nt = (g >> 6) & 3, kt = g >> 8;
    int n = nt * 16 + (l & 15);
    int k0 = kt * 32 + (l >> 4) * 8;
    const float4* ps = (const float4*)(token + (size_t)n * HID + k0);
    float4 a = ps[0], b = ps[1];
    half8 v;
    v[0]=(_Float16)a.x; v[1]=(_Float16)a.y; v[2]=(_Float16)a.z; v[3]=(_Float16)a.w;
    v[4]=(_Float16)b.x; v[5]=(_Float16)b.y; v[6]=(_Float16)b.z; v[7]=(_Float16)b.w;
    h0p[g] = v;
    if (g < G4) bsum[g] = bih[g] + bhh[g];
    if (g < NFLAGS) flags[g] = 0u;
}

// ---- the persistent kernel ----
__global__ __launch_bounds__(512, 2)
void k_lstm(const float* __restrict__ wih, const float* __restrict__ whh,
            const float* __restrict__ bsum, const float* __restrict__ wout,
            _Float16* __restrict__ hbuf,     // (steps+1) slots, fragment layout
            float* __restrict__ ypart,       // [steps][NCU][64]
            unsigned* __restrict__ flags, int steps) {
    extern __shared__ char smem[];
    half8* Wlds = (half8*)smem;
    f32x4* red4 = (f32x4*)(smem + 131072);

    const int tid  = threadIdx.x;
    const int blk  = blockIdx.x;
    const int lane = tid & 63;
    const int w    = tid >> 6;        // wave 0..7
    const int half = w & 1;           // n-tile pair: nt in {2*half, 2*half+1}
    const int ks   = w >> 1;          // k-split slice 0..3 (512 k each)
    const int q    = lane >> 4;       // C-frag row quad 0..3
    const int col  = lane & 15;       // C-frag col (n within tile)

    // prologue: stage W_hh rows for this block's 32 gate-rows as fp16 A-frags
    for (int idx = tid; idx < 2 * 64 * 64; idx += 512) {
        int l = idx & 63, kt = (idx >> 6) & 63, m2 = idx >> 12;
        int m = l & 15;
        int gate = m2 * 2 + (m >> 3);
        int row  = gate * HID + blk * 8 + (m & 7);
        int colw = kt * 32 + (l >> 4) * 8;
        const float4* p = (const float4*)(whh + (size_t)row * HID + colw);
        float4 a = p[0], b = p[1];
        half8 v;
        v[0]=(_Float16)a.x; v[1]=(_Float16)a.y; v[2]=(_Float16)a.z; v[3]=(_Float16)a.w;
        v[4]=(_Float16)b.x; v[5]=(_Float16)b.y; v[6]=(_Float16)b.z; v[7]=(_Float16)b.w;
        Wlds[idx] = v;
    }

    // pointwise-wave (w<2) per-lane constants / state:
    //   rows owned pre-shuffle: mt0 rows 4q+r (biasA), mt1 rows 16+4q+r (biasB)
    //   units owned post-shuffle: (q&1)*4 + r; batch n = half*32 + (q>>1)*16 + col
    float biasA[4] = {0,0,0,0}, biasB[4] = {0,0,0,0}, wj4[4] = {0,0,0,0};
    float c4[4] = {0.0f, 0.0f, 0.0f, 0.0f};
    if (w < 2) {
        #pragma unroll
        for (int r = 0; r < 4; ++r) {
            int rA = 4 * q + r;            // gates row, mt0 (0..15)
            int rB = 16 + 4 * q + r;       // gates row, mt1 (16..31)
            biasA[r] = bsum[(rA >> 3) * HID + blk * 8 + (rA & 7)];
            biasB[r] = bsum[(rB >> 3) * HID + blk * 8 + (rB & 7)];
            wj4[r]   = wout[blk * 8 + (q & 1) * 4 + r];
        }
    }
    __syncthreads();

    for (int t = 0; t < steps; ++t) {
        if (t) {
            // per-slice wait: wave (ks,half) consumes pieces (p, n in its half)
            // for producers p in [ks*64, ks*64+64). Lane li waits its flag.
            while (__hip_atomic_load(&flags[half * NCU + ks * 64 + lane],
                                     __ATOMIC_RELAXED, __HIP_MEMORY_SCOPE_AGENT)
                   < (unsigned)t)
                __builtin_amdgcn_s_sleep(1);
            asm volatile("" ::: "memory");   // no h loads hoisted above the spin
        }
        const half8* hp = (const half8*)(hbuf + (size_t)t * HID * BATCH);
        // acc: (mt, nt = 2*half + j)
        f32x4 a00 = {0,0,0,0}, a01 = {0,0,0,0}, a10 = {0,0,0,0}, a11 = {0,0,0,0};
        const int ktb = ks * 16;
        #pragma unroll
        for (int kk = 0; kk < 16; ++kk) {
            int kt = ktb + kk;
            half8 av0 = Wlds[(kt) * 64 + lane];            // mt=0
            half8 av1 = Wlds[(64 + kt) * 64 + lane];       // mt=1
            half8 b0  = hp[(kt * 4 + half * 2 + 0) * 64 + lane];
            half8 b1  = hp[(kt * 4 + half * 2 + 1) * 64 + lane];
            a00 = __builtin_amdgcn_mfma_f32_16x16x32_f16(av0, b0, a00, 0, 0, 0);
            a01 = __builtin_amdgcn_mfma_f32_16x16x32_f16(av0, b1, a01, 0, 0, 0);
            a10 = __builtin_amdgcn_mfma_f32_16x16x32_f16(av1, b0, a10, 0, 0, 0);
            a11 = __builtin_amdgcn_mfma_f32_16x16x32_f16(av1, b1, a11, 0, 0, 0);
        }
        // ---- 2-barrier k-split reduce (4 slices) ----
        if (ks == 1 || ks == 3) {
            int srow = (ks == 3 ? 2 : 0) + half;           // w2,w3 -> 0,1; w6,w7 -> 2,3
            red4[(srow * 4 + 0) * 64 + lane] = a00;
            red4[(srow * 4 + 1) * 64 + lane] = a01;
            red4[(srow * 4 + 2) * 64 + lane] = a10;
            red4[(srow * 4 + 3) * 64 + lane] = a11;
        }
        __syncthreads();                                   // bar1
        if (ks == 0) {
            int srow = half;
            a00 += red4[(srow * 4 + 0) * 64 + lane];
            a01 += red4[(srow * 4 + 1) * 64 + lane];
            a10 += red4[(srow * 4 + 2) * 64 + lane];
            a11 += red4[(srow * 4 + 3) * 64 + lane];
        } else if (ks == 2) {
            int srow = 2 + half;
            a00 += red4[(srow * 4 + 0) * 64 + lane];
            a01 += red4[(srow * 4 + 1) * 64 + lane];
            a10 += red4[(srow * 4 + 2) * 64 + lane];
            a11 += red4[(srow * 4 + 3) * 64 + lane];
            int sdst = 4 + half;
            red4[(sdst * 4 + 0) * 64 + lane] = a00;
            red4[(sdst * 4 + 1) * 64 + lane] = a01;
            red4[(sdst * 4 + 2) * 64 + lane] = a10;
            red4[(sdst * 4 + 3) * 64 + lane] = a11;
        }
        __syncthreads();                                   // bar2
        if (w < 2) {
            int srow = 4 + half;
            a00 += red4[(srow * 4 + 0) * 64 + lane];
            a01 += red4[(srow * 4 + 1) * 64 + lane];
            a10 += red4[(srow * 4 + 2) * 64 + lane];
            a11 += red4[(srow * 4 + 3) * 64 + lane];
            // bias (per gates-row; same row for both n-tiles)
            #pragma unroll
            for (int r = 0; r < 4; ++r) {
                a00[r] += biasA[r]; a01[r] += biasA[r];
                a10[r] += biasB[r]; a11[r] += biasB[r];
            }
            // cross-half exchange: partner lane^32 holds the other gate pair.
            // q<2 own (i,g) rows, partner has (f,o); q>=2 own (f,o), partner (i,g).
            float x00[4], x01[4], x10[4], x11[4];
            #pragma unroll
            for (int r = 0; r < 4; ++r) {
                x00[r] = __shfl_xor(a00[r], 32);
                x01[r] = __shfl_xor(a01[r], 32);
                x10[r] = __shfl_xor(a10[r], 32);
                x11[r] = __shfl_xor(a11[r], 32);
            }
            const bool lo = (lane < 32);   // q<2: handle n_lo via a00/a10 family
            float hv[4];
            #pragma unroll
            for (int r = 0; r < 4; ++r) {
                float gi = lo ? a00[r] : x01[r];
                float gf = lo ? x00[r] : a01[r];
                float gg = lo ? a10[r] : x11[r];
                float go = lo ? x10[r] : a11[r];
                float iv = 1.0f / (1.0f + __expf(-gi));
                float fv = 1.0f / (1.0f + __expf(-gf));
                float eg = __expf(2.0f * gg);
                float gv = 1.0f - 2.0f / (eg + 1.0f);      // tanh(gg)
                float ov = 1.0f / (1.0f + __expf(-go));
                c4[r] = fv * c4[r] + iv * gv;
                float ec = __expf(2.0f * c4[r]);
                float th = 1.0f - 2.0f / (ec + 1.0f);      // tanh(c)
                hv[r] = ov * th;
            }
            if (t < steps - 1) {
                // pack 4 f16 -> one 8B agent-scope store; lane pairs (q0,q1)
                // and (q2,q3) fill each 16B piece (units 0-3 | 4-7).
                union { unsigned short us[4]; unsigned long long ull; } pk;
                #pragma unroll
                for (int r = 0; r < 4; ++r) {
                    _Float16 hf = (_Float16)hv[r];
                    pk.us[r] = *(unsigned short*)&hf;
                }
                const int nt = half * 2 + (q >> 1);        // global n-tile
                const size_t g = (size_t)((blk >> 2) * 4 + nt) * 64
                               + (blk & 3) * 16 + col;
                unsigned long long* dst = (unsigned long long*)
                    (hbuf + (size_t)(t + 1) * HID * BATCH + g * 8) + (q & 1);
                __hip_atomic_store(dst, pk.ull, __ATOMIC_RELAXED,
                                   __HIP_MEMORY_SCOPE_AGENT);
                asm volatile("s_waitcnt vmcnt(0)" ::: "memory");  // h at coherence pt
                if (lane == 0)
                    __hip_atomic_store(&flags[half * NCU + blk], (unsigned)(t + 1),
                                       __ATOMIC_RELAXED, __HIP_MEMORY_SCOPE_AGENT);
            }
            // y partial (off the critical path, after flag release)
            float yp = wj4[0] * hv[0] + wj4[1] * hv[1]
                     + wj4[2] * hv[2] + wj4[3] * hv[3];
            yp += __shfl_xor(yp, 16);                      // combine unit halves
            if ((q & 1) == 0)
                ypart[((size_t)t * NCU + blk) * 64
                      + half * 32 + (q >> 1) * 16 + col] = yp;
        }
        if (t == 0) {
            // upgrade Wlds in place: W_hh -> W_sum (+= W_ih); must complete in
            // ALL waves before any wave's step-1 MFMA -> block barrier after.
            for (int idx = tid; idx < 2 * 64 * 64; idx += 512) {
                int l = idx & 63, kt = (idx >> 6) & 63, m2 = idx >> 12;
                int m = l & 15;
                int gate = m2 * 2 + (m >> 3);
                int row  = gate * HID + blk * 8 + (m & 7);
                int colw = kt * 32 + (l >> 4) * 8;
                const float4* p = (const float4*)(wih + (size_t)row * HID + colw);
                float4 a = p[0], b = p[1];
                half8 v = Wlds[idx];
                v[0] = (_Float16)((float)v[0] + a.x); v[1] = (_Float16)((float)v[1] + a.y);
                v[2] = (_Float16)((float)v[2] + a.z); v[3] = (_Float16)((float)v[3] + a.w);
                v[4] = (_Float16)((float)v[4] + b.x); v[5] = (_Float16)((float)v[5] + b.y);
                v[6] = (_Float16)((float)v[6] + b.z); v[7] = (_Float16)((float)v[7] + b.w);
                Wlds[idx] = v;
            }
            __syncthreads();
        }
    }
}

// ---- final: out[b][t] = bout + sum over 256 CU partials ----
__global__ __launch_bounds__(512)
void k_yout(const float* __restrict__ ypart, const float* __restrict__ bout,
            float* __restrict__ out, int steps) {
    __shared__ float red[8][64];
    int t = blockIdx.x;
    int tid = threadIdx.x;
    int b = tid & 63, ch = tid >> 6;               // 8 chunks x 32 CUs
    const float* p = ypart + (size_t)t * NCU * 64 + b;
    float s = 0.0f;
    #pragma unroll 8
    for (int cu = ch * 32; cu < ch * 32 + 32; ++cu) s += p[(size_t)cu * 64];
    red[ch][b] = s;
    __syncthreads();
    if (tid < 64) {
        float r = bout[0];
        #pragma unroll
        for (int u = 0; u < 8; ++u) r += red[u][tid];
        out[(size_t)tid * steps + t] = r;
    }
}

extern "C" void kernel_launch(void* const* d_in, const int* in_sizes, int n_in,
                              void* d_out, int out_size, void* d_ws, size_t ws_size,
                              hipStream_t stream) {
    const float* token = (const float*)d_in[0];
    const float* wih   = (const float*)d_in[2];
    const float* whh   = (const float*)d_in[3];
    const float* bih   = (const float*)d_in[4];
    const float* bhh   = (const float*)d_in[5];
    const float* wout  = (const float*)d_in[6];
    const float* bout  = (const float*)d_in[7];
    float* out = (float*)d_out;
    const int steps = out_size / BATCH;            // 30

    char* ws = (char*)d_ws;
    size_t off = 0;
    auto carve = [&](size_t bytes) -> void* {
        void* p = ws + off;
        off = (off + bytes + 255) & ~(size_t)255;
        return p;
    };
    _Float16* hbuf  = (_Float16*)carve((size_t)(steps + 1) * HID * BATCH * 2); // ~8 MB
    float*    bsum  = (float*)carve((size_t)G4 * 4);                   // 32 KB
    float*    ypart = (float*)carve((size_t)steps * NCU * 64 * 4);     // ~2 MB
    unsigned* flags = (unsigned*)carve(NFLAGS * 4);

    hipFuncSetAttribute(reinterpret_cast<const void*>(&k_lstm),
                        hipFuncAttributeMaxDynamicSharedMemorySize, LDS_BYTES);

    k_init<<<dim3(HGRP / 256), dim3(256), 0, stream>>>(
        token, bih, bhh, (half8*)hbuf, bsum, flags);

    k_lstm<<<dim3(NCU), dim3(512), LDS_BYTES, stream>>>(
        wih, whh, bsum, wout, hbuf, ypart, flags, steps);

    k_yout<<<dim3(steps), dim3(512), 0, stream>>>(ypart, bout, out, steps);
}

// Round 5
// 440.593 us; speedup vs baseline: 1.0371x; 1.0371x over previous
//
#include <hip/hip_runtime.h>
#include <cmath>

// Persistent weight-stationary LSTM decode. B=64, H=2048, steps=30.
// gates_t = W_sum @ h_t (t>=1, since x_t == h_t), W_hh @ h_0 at t=0.
// One block per CU (grid=256); weights live in LDS as fp16 MFMA A-frags.
//
// v9 = v8 + register prefetch of ALL 32 h B-frags.
// v8 post-mortem: deleting 3/5 barriers + the whole LDS tail was NEUTRAL
// (bank conflicts 920K->0, WRITE -44%, dur unchanged) => reduce/barriers
// never were the bottleneck. VGPR=68 says the compiler kept only ~6-8
// h-loads in flight inside the MFMA loop => ~32/7 x ~1000cy serialized
// LLC latency per wave per step. Fix: issue all 32 global_load_dwordx4
// back-to-back into registers right after spin-exit (static indices,
// full unroll), then MFMA against registers. 128 VGPR prefetch fits the
// 256-VGPR budget of __launch_bounds__(512,2).

#define HID   2048
#define BATCH 64
#define G4    8192
#define NCU   256                 // persistent grid size == CU count
#define HGRP  (HID * BATCH / 8)   // half8 groups per h slot
#define NFLAGS 512                // [half][block]

typedef __attribute__((ext_vector_type(8))) _Float16 half8;
typedef __attribute__((ext_vector_type(4))) float f32x4;

// LDS layout (bytes):
//   [0,      131072)  Wlds : half8 frags [(mt*64+kt)*64+lane]
//   [131072, 155648)  red4 : f32x4 [(srow*4+p)*64+lane]  (6 srows, 24KB)
#define LDS_BYTES 155648

// ---- init: pack token -> h slot 0 (B-fragment layout), bsum, flags ----
__global__ void k_init(const float* __restrict__ token, const float* __restrict__ bih,
                       const float* __restrict__ bhh, half8* __restrict__ h0p,
                       float* __restrict__ bsum, unsigned* __restrict__ flags) {
    int g = blockIdx.x * 256 + threadIdx.x;          // [0, 16384)
    int l = g & 63, nt = (g >> 6) & 3, kt = g >> 8;
    int n = nt * 16 + (l & 15);
    int k0 = kt * 32 + (l >> 4) * 8;
    const float4* ps = (const float4*)(token + (size_t)n * HID + k0);
    float4 a = ps[0], b = ps[1];
    half8 v;
    v[0]=(_Float16)a.x; v[1]=(_Float16)a.y; v[2]=(_Float16)a.z; v[3]=(_Float16)a.w;
    v[4]=(_Float16)b.x; v[5]=(_Float16)b.y; v[6]=(_Float16)b.z; v[7]=(_Float16)b.w;
    h0p[g] = v;
    if (g < G4) bsum[g] = bih[g] + bhh[g];
    if (g < NFLAGS) flags[g] = 0u;
}

// ---- the persistent kernel ----
__global__ __launch_bounds__(512, 2)
void k_lstm(const float* __restrict__ wih, const float* __restrict__ whh,
            const float* __restrict__ bsum, const float* __restrict__ wout,
            _Float16* __restrict__ hbuf,     // (steps+1) slots, fragment layout
            float* __restrict__ ypart,       // [steps][NCU][64]
            unsigned* __restrict__ flags, int steps) {
    extern __shared__ char smem[];
    half8* Wlds = (half8*)smem;
    f32x4* red4 = (f32x4*)(smem + 131072);

    const int tid  = threadIdx.x;
    const int blk  = blockIdx.x;
    const int lane = tid & 63;
    const int w    = tid >> 6;        // wave 0..7
    const int half = w & 1;           // n-tile pair: nt in {2*half, 2*half+1}
    const int ks   = w >> 1;          // k-split slice 0..3 (512 k each)
    const int q    = lane >> 4;       // C-frag row quad 0..3
    const int col  = lane & 15;       // C-frag col (n within tile)

    // prologue: stage W_hh rows for this block's 32 gate-rows as fp16 A-frags
    for (int idx = tid; idx < 2 * 64 * 64; idx += 512) {
        int l = idx & 63, kt = (idx >> 6) & 63, m2 = idx >> 12;
        int m = l & 15;
        int gate = m2 * 2 + (m >> 3);
        int row  = gate * HID + blk * 8 + (m & 7);
        int colw = kt * 32 + (l >> 4) * 8;
        const float4* p = (const float4*)(whh + (size_t)row * HID + colw);
        float4 a = p[0], b = p[1];
        half8 v;
        v[0]=(_Float16)a.x; v[1]=(_Float16)a.y; v[2]=(_Float16)a.z; v[3]=(_Float16)a.w;
        v[4]=(_Float16)b.x; v[5]=(_Float16)b.y; v[6]=(_Float16)b.z; v[7]=(_Float16)b.w;
        Wlds[idx] = v;
    }

    // pointwise-wave (w<2) per-lane constants / state:
    //   rows owned pre-shuffle: mt0 rows 4q+r (biasA), mt1 rows 16+4q+r (biasB)
    //   units owned post-shuffle: (q&1)*4 + r; batch n = half*32 + (q>>1)*16 + col
    float biasA[4] = {0,0,0,0}, biasB[4] = {0,0,0,0}, wj4[4] = {0,0,0,0};
    float c4[4] = {0.0f, 0.0f, 0.0f, 0.0f};
    if (w < 2) {
        #pragma unroll
        for (int r = 0; r < 4; ++r) {
            int rA = 4 * q + r;            // gates row, mt0 (0..15)
            int rB = 16 + 4 * q + r;       // gates row, mt1 (16..31)
            biasA[r] = bsum[(rA >> 3) * HID + blk * 8 + (rA & 7)];
            biasB[r] = bsum[(rB >> 3) * HID + blk * 8 + (rB & 7)];
            wj4[r]   = wout[blk * 8 + (q & 1) * 4 + r];
        }
    }
    __syncthreads();

    for (int t = 0; t < steps; ++t) {
        if (t) {
            // per-slice wait: wave (ks,half) consumes pieces (p, n in its half)
            // for producers p in [ks*64, ks*64+64). Lane li waits its flag.
            while (__hip_atomic_load(&flags[half * NCU + ks * 64 + lane],
                                     __ATOMIC_RELAXED, __HIP_MEMORY_SCOPE_AGENT)
                   < (unsigned)t)
                __builtin_amdgcn_s_sleep(1);
            asm volatile("" ::: "memory");   // no h loads hoisted above the spin
        }
        const half8* hp = (const half8*)(hbuf + (size_t)t * HID * BATCH);
        const int ktb = ks * 16;
        // ---- issue ALL 32 B-frag loads back-to-back (max MLP) ----
        half8 bfr[32];
        #pragma unroll
        for (int kk = 0; kk < 16; ++kk) {
            bfr[2 * kk + 0] = hp[((ktb + kk) * 4 + half * 2 + 0) * 64 + lane];
            bfr[2 * kk + 1] = hp[((ktb + kk) * 4 + half * 2 + 1) * 64 + lane];
        }
        // acc: (mt, nt = 2*half + j)
        f32x4 a00 = {0,0,0,0}, a01 = {0,0,0,0}, a10 = {0,0,0,0}, a11 = {0,0,0,0};
        #pragma unroll
        for (int kk = 0; kk < 16; ++kk) {
            int kt = ktb + kk;
            half8 av0 = Wlds[(kt) * 64 + lane];            // mt=0
            half8 av1 = Wlds[(64 + kt) * 64 + lane];       // mt=1
            a00 = __builtin_amdgcn_mfma_f32_16x16x32_f16(av0, bfr[2 * kk + 0], a00, 0, 0, 0);
            a01 = __builtin_amdgcn_mfma_f32_16x16x32_f16(av0, bfr[2 * kk + 1], a01, 0, 0, 0);
            a10 = __builtin_amdgcn_mfma_f32_16x16x32_f16(av1, bfr[2 * kk + 0], a10, 0, 0, 0);
            a11 = __builtin_amdgcn_mfma_f32_16x16x32_f16(av1, bfr[2 * kk + 1], a11, 0, 0, 0);
        }
        // ---- 2-barrier k-split reduce (4 slices) ----
        if (ks == 1 || ks == 3) {
            int srow = (ks == 3 ? 2 : 0) + half;           // w2,w3 -> 0,1; w6,w7 -> 2,3
            red4[(srow * 4 + 0) * 64 + lane] = a00;
            red4[(srow * 4 + 1) * 64 + lane] = a01;
            red4[(srow * 4 + 2) * 64 + lane] = a10;
            red4[(srow * 4 + 3) * 64 + lane] = a11;
        }
        __syncthreads();                                   // bar1
        if (ks == 0) {
            int srow = half;
            a00 += red4[(srow * 4 + 0) * 64 + lane];
            a01 += red4[(srow * 4 + 1) * 64 + lane];
            a10 += red4[(srow * 4 + 2) * 64 + lane];
            a11 += red4[(srow * 4 + 3) * 64 + lane];
        } else if (ks == 2) {
            int srow = 2 + half;
            a00 += red4[(srow * 4 + 0) * 64 + lane];
            a01 += red4[(srow * 4 + 1) * 64 + lane];
            a10 += red4[(srow * 4 + 2) * 64 + lane];
            a11 += red4[(srow * 4 + 3) * 64 + lane];
            int sdst = 4 + half;
            red4[(sdst * 4 + 0) * 64 + lane] = a00;
            red4[(sdst * 4 + 1) * 64 + lane] = a01;
            red4[(sdst * 4 + 2) * 64 + lane] = a10;
            red4[(sdst * 4 + 3) * 64 + lane] = a11;
        }
        __syncthreads();                                   // bar2
        if (w < 2) {
            int srow = 4 + half;
            a00 += red4[(srow * 4 + 0) * 64 + lane];
            a01 += red4[(srow * 4 + 1) * 64 + lane];
            a10 += red4[(srow * 4 + 2) * 64 + lane];
            a11 += red4[(srow * 4 + 3) * 64 + lane];
            // bias (per gates-row; same row for both n-tiles)
            #pragma unroll
            for (int r = 0; r < 4; ++r) {
                a00[r] += biasA[r]; a01[r] += biasA[r];
                a10[r] += biasB[r]; a11[r] += biasB[r];
            }
            // cross-half exchange: partner lane^32 holds the other gate pair.
            // q<2 own (i,g) rows, partner has (f,o); q>=2 own (f,o), partner (i,g).
            float x00[4], x01[4], x10[4], x11[4];
            #pragma unroll
            for (int r = 0; r < 4; ++r) {
                x00[r] = __shfl_xor(a00[r], 32);
                x01[r] = __shfl_xor(a01[r], 32);
                x10[r] = __shfl_xor(a10[r], 32);
                x11[r] = __shfl_xor(a11[r], 32);
            }
            const bool lo = (lane < 32);   // q<2: handle n_lo via a00/a10 family
            float hv[4];
            #pragma unroll
            for (int r = 0; r < 4; ++r) {
                float gi = lo ? a00[r] : x01[r];
                float gf = lo ? x00[r] : a01[r];
                float gg = lo ? a10[r] : x11[r];
                float go = lo ? x10[r] : a11[r];
                float iv = 1.0f / (1.0f + __expf(-gi));
                float fv = 1.0f / (1.0f + __expf(-gf));
                float eg = __expf(2.0f * gg);
                float gv = 1.0f - 2.0f / (eg + 1.0f);      // tanh(gg)
                float ov = 1.0f / (1.0f + __expf(-go));
                c4[r] = fv * c4[r] + iv * gv;
                float ec = __expf(2.0f * c4[r]);
                float th = 1.0f - 2.0f / (ec + 1.0f);      // tanh(c)
                hv[r] = ov * th;
            }
            if (t < steps - 1) {
                // pack 4 f16 -> one 8B agent-scope store; lane pairs (q0,q1)
                // and (q2,q3) fill each 16B piece (units 0-3 | 4-7).
                union { unsigned short us[4]; unsigned long long ull; } pk;
                #pragma unroll
                for (int r = 0; r < 4; ++r) {
                    _Float16 hf = (_Float16)hv[r];
                    pk.us[r] = *(unsigned short*)&hf;
                }
                const int nt = half * 2 + (q >> 1);        // global n-tile
                const size_t g = (size_t)((blk >> 2) * 4 + nt) * 64
                               + (blk & 3) * 16 + col;
                unsigned long long* dst = (unsigned long long*)
                    (hbuf + (size_t)(t + 1) * HID * BATCH + g * 8) + (q & 1);
                __hip_atomic_store(dst, pk.ull, __ATOMIC_RELAXED,
                                   __HIP_MEMORY_SCOPE_AGENT);
                asm volatile("s_waitcnt vmcnt(0)" ::: "memory");  // h at coherence pt
                if (lane == 0)
                    __hip_atomic_store(&flags[half * NCU + blk], (unsigned)(t + 1),
                                       __ATOMIC_RELAXED, __HIP_MEMORY_SCOPE_AGENT);
            }
            // y partial (off the critical path, after flag release)
            float yp = wj4[0] * hv[0] + wj4[1] * hv[1]
                     + wj4[2] * hv[2] + wj4[3] * hv[3];
            yp += __shfl_xor(yp, 16);                      // combine unit halves
            if ((q & 1) == 0)
                ypart[((size_t)t * NCU + blk) * 64
                      + half * 32 + (q >> 1) * 16 + col] = yp;
        }
        if (t == 0) {
            // upgrade Wlds in place: W_hh -> W_sum (+= W_ih); must complete in
            // ALL waves before any wave's step-1 MFMA -> block barrier after.
            for (int idx = tid; idx < 2 * 64 * 64; idx += 512) {
                int l = idx & 63, kt = (idx >> 6) & 63, m2 = idx >> 12;
                int m = l & 15;
                int gate = m2 * 2 + (m >> 3);
                int row  = gate * HID + blk * 8 + (m & 7);
                int colw = kt * 32 + (l >> 4) * 8;
                const float4* p = (const float4*)(wih + (size_t)row * HID + colw);
                float4 a = p[0], b = p[1];
                half8 v = Wlds[idx];
                v[0] = (_Float16)((float)v[0] + a.x); v[1] = (_Float16)((float)v[1] + a.y);
                v[2] = (_Float16)((float)v[2] + a.z); v[3] = (_Float16)((float)v[3] + a.w);
                v[4] = (_Float16)((float)v[4] + b.x); v[5] = (_Float16)((float)v[5] + b.y);
                v[6] = (_Float16)((float)v[6] + b.z); v[7] = (_Float16)((float)v[7] + b.w);
                Wlds[idx] = v;
            }
            __syncthreads();
        }
    }
}

// ---- final: out[b][t] = bout + sum over 256 CU partials ----
__global__ __launch_bounds__(512)
void k_yout(const float* __restrict__ ypart, const float* __restrict__ bout,
            float* __restrict__ out, int steps) {
    __shared__ float red[8][64];
    int t = blockIdx.x;
    int tid = threadIdx.x;
    int b = tid & 63, ch = tid >> 6;               // 8 chunks x 32 CUs
    const float* p = ypart + (size_t)t * NCU * 64 + b;
    float s = 0.0f;
    #pragma unroll 8
    for (int cu = ch * 32; cu < ch * 32 + 32; ++cu) s += p[(size_t)cu * 64];
    red[ch][b] = s;
    __syncthreads();
    if (tid < 64) {
        float r = bout[0];
        #pragma unroll
        for (int u = 0; u < 8; ++u) r += red[u][tid];
        out[(size_t)tid * steps + t] = r;
    }
}

extern "C" void kernel_launch(void* const* d_in, const int* in_sizes, int n_in,
                              void* d_out, int out_size, void* d_ws, size_t ws_size,
                              hipStream_t stream) {
    const float* token = (const float*)d_in[0];
    const float* wih   = (const float*)d_in[2];
    const float* whh   = (const float*)d_in[3];
    const float* bih   = (const float*)d_in[4];
    const float* bhh   = (const float*)d_in[5];
    const float* wout  = (const float*)d_in[6];
    const float* bout  = (const float*)d_in[7];
    float* out = (float*)d_out;
    const int steps = out_size / BATCH;            // 30

    char* ws = (char*)d_ws;
    size_t off = 0;
    auto carve = [&](size_t bytes) -> void* {
        void* p = ws + off;
        off = (off + bytes + 255) & ~(size_t)255;
        return p;
    };
    _Float16* hbuf  = (_Float16*)carve((size_t)(steps + 1) * HID * BATCH * 2); // ~8 MB
    float*    bsum  = (float*)carve((size_t)G4 * 4);                   // 32 KB
    float*    ypart = (float*)carve((size_t)steps * NCU * 64 * 4);     // ~2 MB
    unsigned* flags = (unsigned*)carve(NFLAGS * 4);

    hipFuncSetAttribute(reinterpret_cast<const void*>(&k_lstm),
                        hipFuncAttributeMaxDynamicSharedMemorySize, LDS_BYTES);

    k_init<<<dim3(HGRP / 256), dim3(256), 0, stream>>>(
        token, bih, bhh, (half8*)hbuf, bsum, flags);

    k_lstm<<<dim3(NCU), dim3(512), LDS_BYTES, stream>>>(
        wih, whh, bsum, wout, hbuf, ypart, flags, steps);

    k_yout<<<dim3(steps), dim3(512), 0, stream>>>(ypart, bout, out, steps);
}